// Round 9
// baseline (214.589 us; speedup 1.0000x reference)
//
#include <hip/hip_runtime.h>
#include <stdint.h>

// SVDQuant forward on MI355X:
//   y = Q4(x*smooth) @ Q4(Wres)^T + (x*smooth) @ lora_down @ lora_up^T + bias
// R12 structure (2 kernels):
//   K1 prep_kernel (grid 3072, unchanged from R11): 37 KiB LDS, 4 blocks/CU.
//   K2 gemm_kernel R12: TLP route. Non-gemm ~133us is fixed-ish harness cost;
//     gemm at 70.5us = 55% of its LDS-pipe floor (39us), gap = tile-end
//     vmcnt+barrier drain with 1 block/CU (nothing co-resident to issue).
//     New shape: 256x128 tile, BK=32, 512 thr (8 waves 4Mx2N, wave-tile 64x64),
//     3-buffer LDS ring 72 KiB -> 2 blocks/CU, grid 512 -> block B's MFMAs
//     cover block A's drain (m114/m97 cross-block overlap). Min-barrier
//     lifecycle kept: stage tile t+2 at tile top, ONE counted vmcnt(3)+barrier
//     per tile (t+2's 3 loads in flight, t+1 certified). R5-verified BK=32
//     swizzle (csrc=(tid&3)^((tid>>3)&3), read ck=quad^((l16>>1)&3) -> 2-way
//     max, free). XCD-chunked blockIdx (512 = 8 XCD x 64 = 4M x 16N panels).

typedef __attribute__((ext_vector_type(8))) short short8;
typedef __attribute__((ext_vector_type(8))) unsigned short ushort8;
typedef __attribute__((ext_vector_type(4))) unsigned short ushort4v;
typedef __attribute__((ext_vector_type(4))) float floatx4;

#define M_TOK 8192
#define K_IN  2048
#define N_OUT 2048
#define RANK  32
#define KC    2112      // 2048 quant + 32 lowrank + 32 zero pad = 66 * 32
#define NTILE 66        // K-tiles of 32
#define XS_STRIDE 2056  // LDS x_s row stride (shorts): +8 -> 4-bank row rotation
#define XROWS 8         // x-rows per prep block

// round-to-nearest-even f32 -> bf16 (finite inputs only)
__device__ __forceinline__ unsigned short f2bf(float f) {
  unsigned int u = __float_as_uint(f);
  u += 0x7fff + ((u >> 16) & 1);
  return (unsigned short)(u >> 16);
}

// fakequant 8 values held by this lane; group of 64 = 8 consecutive lanes
__device__ __forceinline__ void quant8(const float* v, unsigned short* q) {
  float amax = 0.f;
#pragma unroll
  for (int i = 0; i < 8; ++i) amax = fmaxf(amax, fabsf(v[i]));
  amax = fmaxf(amax, __shfl_xor(amax, 1, 64));
  amax = fmaxf(amax, __shfl_xor(amax, 2, 64));
  amax = fmaxf(amax, __shfl_xor(amax, 4, 64));
  float scale = fmaxf(amax / 7.0f, 1e-8f);
#pragma unroll
  for (int i = 0; i < 8; ++i) {
    float qq = rintf(v[i] / scale);   // IEEE div + RNE == jnp.round(g/scale)
    qq = fminf(fmaxf(qq, -7.f), 7.f);
    q[i] = f2bf(qq * scale);
  }
}

// ---------------- K1: fused prep (unchanged from R11) -----------------------
__global__ __launch_bounds__(256) void prep_kernel(const float* __restrict__ x,
                                                   const float* __restrict__ smooth,
                                                   const float* __restrict__ wgt,
                                                   const float* __restrict__ ld,
                                                   const float* __restrict__ lup,
                                                   unsigned short* __restrict__ Xcat,
                                                   unsigned short* __restrict__ Wcat) {
  __shared__ unsigned short xs[XROWS * XS_STRIDE];  // 32.9 KiB bf16 x_s
  __shared__ float red[4][XROWS][32];               // 4 KiB
  int tid = threadIdx.x;

  if (blockIdx.x >= 1024) {
    // ---- W path: one row of Wres per block (no LDS use) ----
    int row = blockIdx.x - 1024;
    const float4* wr = (const float4*)(wgt + (size_t)row * K_IN);
    float4 a0 = wr[tid * 2], a1 = wr[tid * 2 + 1];
    float v[8] = {a0.x, a0.y, a0.z, a0.w, a1.x, a1.y, a1.z, a1.w};
    ushort8 q;
    quant8(v, (unsigned short*)&q);
    *(ushort8*)(Wcat + (size_t)row * KC + tid * 8) = q;
    if (tid < 32)      Wcat[(size_t)row * KC + 2048 + tid] = f2bf(lup[row * RANK + tid]);
    else if (tid < 64) Wcat[(size_t)row * KC + 2048 + tid] = 0;
    return;
  }

  // ---- X path: 8 rows per block ----
  int rowbase = blockIdx.x * XROWS;
  int w = tid >> 6, lane = tid & 63, quad = lane >> 4, l16 = lane & 15;

  // Phase A: coalesced quantize, one row per pass (256 thr x 8 elems = 2048)
  const float4* sr = (const float4*)smooth;
  float4 s0 = sr[tid * 2], s1 = sr[tid * 2 + 1];
#pragma unroll 2
  for (int r = 0; r < XROWS; ++r) {
    const float4* xr = (const float4*)(x + (size_t)(rowbase + r) * K_IN);
    float4 a0 = xr[tid * 2], a1 = xr[tid * 2 + 1];
    float v[8] = {a0.x * s0.x, a0.y * s0.y, a0.z * s0.z, a0.w * s0.w,
                  a1.x * s1.x, a1.y * s1.y, a1.z * s1.z, a1.w * s1.w};
    ushort8 q;
    quant8(v, (unsigned short*)&q);
    *(ushort8*)(Xcat + (size_t)(rowbase + r) * KC + tid * 8) = q;
    ushort8 sb;
#pragma unroll
    for (int t = 0; t < 8; ++t) sb[t] = f2bf(v[t]);
    *(ushort8*)(xs + r * XS_STRIDE + tid * 8) = sb;
  }
  // zero pad Xcat[:, 2080:2112): rows 0..7, 16 threads x 4B per row
  if (tid < 128)
    *(unsigned int*)(Xcat + (size_t)(rowbase + (tid >> 4)) * KC + 2080 + (tid & 15) * 2) = 0u;
  __syncthreads();

  // Phase B: t = x_s @ lora_down. wave w covers k in [w*512, w*512+512).
  // A-frag row clamped to l16&7 (8 real rows); C rows 8-15 are discarded.
  floatx4 acc[2];
  acc[0] = (floatx4)0.f;
  acc[1] = (floatx4)0.f;
  int kbase = w * 512;
  int arow = (l16 & 7) * XS_STRIDE;
#pragma unroll 2
  for (int it = 0; it < 16; ++it) {
    int k = kbase + it * 32 + quad * 8;
    short8 af = *(const short8*)(xs + arow + k);
    // B-frag straight from lora_down [k][r]: B[k=quad*8+j][n=l16 (+16)]
    short8 b0, b1;
#pragma unroll
    for (int j = 0; j < 8; ++j) {
      b0[j] = (short)f2bf(ld[(size_t)(k + j) * RANK + l16]);
      b1[j] = (short)f2bf(ld[(size_t)(k + j) * RANK + 16 + l16]);
    }
    acc[0] = __builtin_amdgcn_mfma_f32_16x16x32_bf16(af, b0, acc[0], 0, 0, 0);
    acc[1] = __builtin_amdgcn_mfma_f32_16x16x32_bf16(af, b1, acc[1], 0, 0, 0);
  }
  // C layout: row = quad*4 + r, col = l16 (+16 for acc[1]); keep rows < 8
#pragma unroll
  for (int nt = 0; nt < 2; ++nt)
#pragma unroll
    for (int r = 0; r < 4; ++r) {
      int row = quad * 4 + r;
      if (row < XROWS) red[w][row][nt * 16 + l16] = acc[nt][r];
    }
  __syncthreads();
  if (tid < 64) {
    int rl = tid >> 3, seg = tid & 7;  // row 0..7, col segment of 4
    ushort4v o;
#pragma unroll
    for (int j = 0; j < 4; ++j) {
      int c = seg * 4 + j;
      float s = red[0][rl][c] + red[1][rl][c] + red[2][rl][c] + red[3][rl][c];
      o[j] = f2bf(s);
    }
    *(ushort4v*)(Xcat + (size_t)(rowbase + rl) * KC + 2048 + seg * 4) = o;
  }
}

// ---------------- K2: main GEMM: out = Xcat @ Wcat^T + bias ----------------
__device__ __forceinline__ void gld_lds16(const unsigned short* g, unsigned short* l) {
  __builtin_amdgcn_global_load_lds(
      (const __attribute__((address_space(1))) unsigned int*)g,
      (__attribute__((address_space(3))) unsigned int*)l, 16, 0, 0);
}

__global__ __launch_bounds__(512, 4) void gemm_kernel(const unsigned short* __restrict__ Xcat,
                                                      const unsigned short* __restrict__ Wcat,
                                                      const float* __restrict__ bias,
                                                      float* __restrict__ out) {
  // ring of 3 K-tile buffers x (A 256x32 + B 128x32) bf16 = 72 KiB -> 2 blk/CU
  __shared__ unsigned short smem[36864];
  int tid = threadIdx.x;
  int w = tid >> 6, lane = tid & 63, quad = lane >> 4, l16 = lane & 15;
  int wm = w >> 1, wn = w & 1;  // 4 M-waves x 2 N-waves; wave tile 64x64

  // Bijective XCD chunking: grid 512 = 8 XCDs x 64; each XCD chunk = 4 M-panels
  // x 16 N-panels -> A/B panel slabs stay L2-resident per XCD.
  int bid = blockIdx.x;
  int wg = (bid & 7) * 64 + (bid >> 3);
  int bM = (wg >> 4) * 256;   // 32 M-panels
  int bN = (wg & 15) * 128;   // 16 N-panels

  // Staging per K32-tile: A = 256 rows x 4 chunks(16B) = 16KB (2 rounds of 128
  // rows), B = 128 rows x 4 chunks = 8KB (1 round). thread -> (row = tid/4,
  // chunk slot = tid&3); source chunk pre-swizzled with (row>>1)&3 ==
  // (tid>>3)&3 so swizzled ds_reads see linear data (R5-verified, 0 conflicts).
  int srow = tid >> 2;                  // 0..127
  int csrc = (tid & 3) ^ ((tid >> 3) & 3);
  const unsigned short* Ag = Xcat + (size_t)(bM + srow) * KC + csrc * 8;
  const unsigned short* Bg = Wcat + (size_t)(bN + srow) * KC + csrc * 8;
  int ldsw = w * 512;                   // wave-uniform dest: lane*16B within

  // fragment LDS offsets (shorts): row*32 + swizzled chunk; (row>>1)&3 == (l16>>1)&3
  int ck = (quad ^ ((l16 >> 1) & 3)) * 8;
  int aoff[4], boff[4];
#pragma unroll
  for (int mt = 0; mt < 4; ++mt) aoff[mt] = (wm * 64 + mt * 16 + l16) * 32 + ck;
#pragma unroll
  for (int nt = 0; nt < 4; ++nt) boff[nt] = 8192 + (wn * 64 + nt * 16 + l16) * 32 + ck;

  floatx4 acc[4][4];
#pragma unroll
  for (int mt = 0; mt < 4; ++mt)
#pragma unroll
    for (int nt = 0; nt < 4; ++nt) acc[mt][nt] = (floatx4)0.f;

  int b0 = 0, b1 = 12288, b2 = 24576;   // ring: read b0, next b1, stage into b2

#define STAGE(tt, OFF)                                                        \
  do {                                                                        \
    int k0_ = (tt) * 32;                                                      \
    gld_lds16(Ag + k0_,            smem + (OFF) + ldsw);                      \
    gld_lds16(Ag + 128 * KC + k0_, smem + (OFF) + 4096 + ldsw);               \
    gld_lds16(Bg + k0_,            smem + (OFF) + 8192 + ldsw);               \
  } while (0)

  // prologue: tiles 0,1 staged; certify tile 0 (3 newest stay in flight)
  STAGE(0, 0);
  STAGE(1, 12288);
  asm volatile("s_waitcnt vmcnt(3)" ::: "memory");
  __builtin_amdgcn_s_barrier();

#pragma unroll 1
  for (int t = 0; t < NTILE; ++t) {
    unsigned short* sb = smem + b0;

    // stage tile t+2 into the dead buffer: ~2 tiles (>HBM latency) of cover
    if (t + 2 < NTILE) STAGE(t + 2, b2);

    short8 a[4], b[4];
#pragma unroll
    for (int mt = 0; mt < 4; ++mt) a[mt] = *(const short8*)(sb + aoff[mt]);
#pragma unroll
    for (int nt = 0; nt < 4; ++nt) b[nt] = *(const short8*)(sb + boff[nt]);

    __builtin_amdgcn_s_setprio(1);
#pragma unroll
    for (int mt = 0; mt < 4; ++mt)
#pragma unroll
      for (int nt = 0; nt < 4; ++nt)
        acc[mt][nt] = __builtin_amdgcn_mfma_f32_16x16x32_bf16(a[mt], b[nt], acc[mt][nt], 0, 0, 0);
    __builtin_amdgcn_s_setprio(0);

    // tile end: certify tile t+1 landed (t+2's 3 loads stay in flight);
    // one counted vmcnt + one barrier per K=32. Co-resident block's MFMAs
    // cover this drain (the R12 bet).
    if (t < NTILE - 2)
      asm volatile("s_waitcnt vmcnt(3)" ::: "memory");
    else if (t == NTILE - 2)
      asm volatile("s_waitcnt vmcnt(0)" ::: "memory");
    if (t + 1 < NTILE) {
      __builtin_amdgcn_s_barrier();
      __builtin_amdgcn_sched_barrier(0);  // nothing crosses the tile boundary
    }
    int tmp = b0; b0 = b1; b1 = b2; b2 = tmp;
  }
#undef STAGE

  // epilogue: + bias, store fp32
#pragma unroll
  for (int nt = 0; nt < 4; ++nt) {
    int col = bN + wn * 64 + nt * 16 + l16;
    float bv = bias[col];
#pragma unroll
    for (int mt = 0; mt < 4; ++mt) {
      int row = bM + wm * 64 + mt * 16 + quad * 4;
#pragma unroll
      for (int r2 = 0; r2 < 4; ++r2)
        out[(size_t)(row + r2) * N_OUT + col] = acc[mt][nt][r2] + bv;
    }
  }
}

extern "C" void kernel_launch(void* const* d_in, const int* in_sizes, int n_in,
                              void* d_out, int out_size, void* d_ws, size_t ws_size,
                              hipStream_t stream) {
  const float* x      = (const float*)d_in[0];
  const float* wgt    = (const float*)d_in[1];
  const float* ld     = (const float*)d_in[2];
  const float* lup    = (const float*)d_in[3];
  const float* smooth = (const float*)d_in[4];
  const float* bias   = (const float*)d_in[5];
  float* out = (float*)d_out;

  unsigned short* Xcat = (unsigned short*)d_ws;                 // 8192*2112*2 = 34.6 MB
  unsigned short* Wcat = Xcat + (size_t)M_TOK * KC;             //  8.65 MB

  hipLaunchKernelGGL(prep_kernel, dim3(1024 + N_OUT), dim3(256), 0, stream,
                     x, smooth, wgt, ld, lup, Xcat, Wcat);
  hipLaunchKernelGGL(gemm_kernel, dim3((M_TOK / 256) * (N_OUT / 128)), dim3(512), 0, stream,
                     Xcat, Wcat, bias, out);
}